// Round 1
// baseline (384.497 us; speedup 1.0000x reference)
//
#include <hip/hip_runtime.h>

// Physics constants (DX = DY = 1 so divisions vanish; DT = 0.01 -> *100)
#define NN 1024
#define CH ((size_t)NN * (size_t)NN)

// torch.gradient first derivative, centered pointer c (points at element i), stride s
__device__ __forceinline__ float d1c(const float* __restrict__ c, int i, int s) {
    if (i == 0)      return c[s] - c[0];
    if (i == NN - 1) return c[0] - c[-s];
    return 0.5f * (c[s] - c[-s]);
}

// gradient-of-gradient second derivative, centered pointer
__device__ __forceinline__ float d2c(const float* __restrict__ c, int i, int s) {
    if (i == 0)      return 0.5f * c[2 * s] - c[s] + 0.5f * c[0];
    if (i == 1)      return 0.25f * c[2 * s] - 0.75f * c[0] + 0.5f * c[-s];
    if (i == NN - 2) return 0.25f * c[-2 * s] - 0.75f * c[0] + 0.5f * c[s];
    if (i == NN - 1) return 0.5f * c[-2 * s] - c[-s] + 0.5f * c[0];
    return 0.25f * (c[2 * s] - 2.0f * c[0] + c[-2 * s]);
}

#define ROWS_PER_BLOCK 8

__global__ __launch_bounds__(256) void physics_residual_kernel(
    const float* __restrict__ fnow, const float* __restrict__ fnext,
    double* __restrict__ part)
{
    const int x  = blockIdx.x * 256 + threadIdx.x;
    const int y0 = blockIdx.y * ROWS_PER_BLOCK;
    const int b  = blockIdx.z;

    float acc = 0.0f;

    for (int y = y0; y < y0 + ROWS_PER_BLOCK; ++y) {
        const size_t base = (size_t)b * 4 * CH + (size_t)y * NN + (size_t)x;
        const float* U  = fnext + base;          // U_next centered at (y,x)
        const float* V  = U + CH;
        const float* T  = V + CH;
        const float* P  = T + CH;
        const float* Un = fnow + base;           // U_now
        const float* Vn = Un + CH;
        const float* Tn = Vn + CH;

        const float u  = U[0],  v  = V[0],  t  = T[0];
        const float un = Un[0], vn = Vn[0], tn = Tn[0];

        const float Udx  = d1c(U, x, 1),  Udy  = d1c(U, y, NN);
        const float Udxx = d2c(U, x, 1),  Udyy = d2c(U, y, NN);
        const float Vdx  = d1c(V, x, 1),  Vdy  = d1c(V, y, NN);
        const float Vdxx = d2c(V, x, 1),  Vdyy = d2c(V, y, NN);
        const float Tdx  = d1c(T, x, 1),  Tdy  = d1c(T, y, NN);
        const float Tdxx = d2c(T, x, 1),  Tdyy = d2c(T, y, NN);
        const float Pdx  = d1c(P, x, 1),  Pdy  = d1c(P, y, NN);

        // continuity
        const float cont = Udx + Vdy;

        // x-momentum: res = dU/dt + conv_x + Pdx - PR*(Udxx+Udyy) + (PR/DA)*U
        const float rx = (u - un) * 100.0f + u * Udx + vn * Udy
                       + Pdx - 0.71f * (Udxx + Udyy) + 7.1f * u;

        // y-momentum: res = dV/dt + conv_y + Pdy - PR*(Vdxx+Vdyy)
        //                  - RA*PR*T + (HA^2*PR + PR/DA)*V
        const float ry = (v - vn) * 100.0f + un * Vdx + v * Vdy
                       + Pdy - 0.71f * (Vdxx + Vdyy)
                       - 710.0f * t + 78.1f * v;

        // energy: res = dT/dt + conv_t - diff_c*(Tdxx+Tdyy) - Q*T
        const float rt = (t - tn) * 100.0f + un * Tdx + vn * Tdy
                       - 1.6666666666666667f * (Tdxx + Tdyy) - 0.1f * t;

        acc += cont * cont + rx * rx + ry * ry + rt * rt;
    }

    // block reduction: wave shuffle -> LDS -> per-block double partial
    double d = (double)acc;
    #pragma unroll
    for (int off = 32; off; off >>= 1) d += __shfl_down(d, off, 64);

    __shared__ double lsum[4];
    const int lane = threadIdx.x & 63;
    const int wv   = threadIdx.x >> 6;
    if (lane == 0) lsum[wv] = d;
    __syncthreads();
    if (threadIdx.x == 0) {
        const int pidx = (blockIdx.z * gridDim.y + blockIdx.y) * gridDim.x + blockIdx.x;
        part[pidx] = lsum[0] + lsum[1] + lsum[2] + lsum[3];
    }
}

__global__ __launch_bounds__(1024) void final_reduce_kernel(
    const double* __restrict__ part, int n, float* __restrict__ out)
{
    double s = 0.0;
    for (int i = threadIdx.x; i < n; i += 1024) s += part[i];

    #pragma unroll
    for (int off = 32; off; off >>= 1) s += __shfl_down(s, off, 64);

    __shared__ double lsum[16];
    const int lane = threadIdx.x & 63;
    const int wv   = threadIdx.x >> 6;
    if (lane == 0) lsum[wv] = s;
    __syncthreads();
    if (threadIdx.x == 0) {
        double tot = 0.0;
        #pragma unroll
        for (int i = 0; i < 16; ++i) tot += lsum[i];
        tot *= (1e-4 / 8388608.0);   // BASE_SCALE / mean-count (same for all 4 terms)
        tot = fmin(fmax(tot, 1e-10), 1.0);
        out[0] = (float)tot;
    }
}

extern "C" void kernel_launch(void* const* d_in, const int* in_sizes, int n_in,
                              void* d_out, int out_size, void* d_ws, size_t ws_size,
                              hipStream_t stream) {
    const float* fnow  = (const float*)d_in[0];
    const float* fnext = (const float*)d_in[1];
    double* part = (double*)d_ws;          // 4096 doubles = 32 KiB scratch
    float*  out  = (float*)d_out;

    dim3 grid(NN / 256, NN / ROWS_PER_BLOCK, 8);   // (4, 128, 8) = 4096 blocks
    physics_residual_kernel<<<grid, 256, 0, stream>>>(fnow, fnext, part);
    final_reduce_kernel<<<1, 1024, 0, stream>>>(part, grid.x * grid.y * grid.z, out);
}

// Round 2
// 282.617 us; speedup vs baseline: 1.3605x; 1.3605x over previous
//
#include <hip/hip_runtime.h>

#define NN 1024
#define CH ((size_t)NN * (size_t)NN)
#define ROWS 8

// ---- float4 elementwise helpers (avoid reliance on HIP operator overloads) ----
__device__ __forceinline__ float4 v_add(float4 a, float4 b) {
    return make_float4(a.x + b.x, a.y + b.y, a.z + b.z, a.w + b.w);
}
__device__ __forceinline__ float4 v_sub(float4 a, float4 b) {
    return make_float4(a.x - b.x, a.y - b.y, a.z - b.z, a.w - b.w);
}
__device__ __forceinline__ float4 v_mul(float4 a, float4 b) {
    return make_float4(a.x * b.x, a.y * b.y, a.z * b.z, a.w * b.w);
}
__device__ __forceinline__ float4 v_fma(float4 a, float4 b, float4 c) {
    return make_float4(fmaf(a.x, b.x, c.x), fmaf(a.y, b.y, c.y),
                       fmaf(a.z, b.z, c.z), fmaf(a.w, b.w, c.w));
}
__device__ __forceinline__ float4 v_fmas(float s, float4 a, float4 c) {
    return make_float4(fmaf(s, a.x, c.x), fmaf(s, a.y, c.y),
                       fmaf(s, a.z, c.z), fmaf(s, a.w, c.w));
}
__device__ __forceinline__ float4 v_scale(float s, float4 a) {
    return make_float4(s * a.x, s * a.y, s * a.z, s * a.w);
}

__device__ __forceinline__ float4 ldf4(const float* p) { return *(const float4*)p; }

__device__ __forceinline__ int clampr(int r) { return r < 0 ? 0 : (r > NN - 1 ? NN - 1 : r); }

// x-derivatives (torch.gradient + gradient-of-gradient) for 4 pixels at x=4*tx..4*tx+3
// l/c/r are the left/center/right float4 of the row. Edge fixups for tx==0 / tx==255.
__device__ __forceinline__ void xder(float4 l, float4 c, float4 r, int tx,
                                     float4& d1, float4& d2) {
    d1.x = 0.5f * (c.y - l.w);
    d1.y = 0.5f * (c.z - c.x);
    d1.z = 0.5f * (c.w - c.y);
    d1.w = 0.5f * (r.x - c.z);
    d2.x = 0.25f * (c.z - 2.0f * c.x + l.z);
    d2.y = 0.25f * (c.w - 2.0f * c.y + l.w);
    d2.z = 0.25f * (r.x - 2.0f * c.z + c.x);
    d2.w = 0.25f * (r.y - 2.0f * c.w + c.y);
    if (tx == 0) {            // pixels x=0 (i=0) and x=1 (i=1)
        d1.x = c.y - c.x;
        d2.x = 0.5f * c.z - c.y + 0.5f * c.x;
        d2.y = 0.25f * c.w - 0.75f * c.y + 0.5f * c.x;
    } else if (tx == NN / 4 - 1) {  // pixels x=1022 (i=n-2) and x=1023 (i=n-1)
        d2.z = 0.25f * c.x - 0.75f * c.z + 0.5f * c.w;
        d1.w = c.w - c.z;
        d2.w = 0.5f * c.y - c.z + 0.5f * c.w;
    }
}

// first-derivative-only variant (for P)
__device__ __forceinline__ void xder1(float4 l, float4 c, float4 r, int tx, float4& d1) {
    d1.x = 0.5f * (c.y - l.w);
    d1.y = 0.5f * (c.z - c.x);
    d1.z = 0.5f * (c.w - c.y);
    d1.w = 0.5f * (r.x - c.z);
    if (tx == 0)               d1.x = c.y - c.x;
    else if (tx == NN / 4 - 1) d1.w = c.w - c.z;
}

// y-derivatives from the 5-row rolling window (w0..w4 = rows y-2..y+2, clamped).
// Branches are wave-uniform (whole block shares y).
__device__ __forceinline__ void yder(float4 w0, float4 w1, float4 w2, float4 w3, float4 w4,
                                     int y, float4& d1, float4& d2) {
    if (y == 0) {
        d1 = v_sub(w3, w2);
        d2 = v_fmas(0.5f, w4, v_fmas(0.5f, w2, v_scale(-1.0f, w3)));
    } else if (y == 1) {
        d1 = v_scale(0.5f, v_sub(w3, w1));
        d2 = v_fmas(0.25f, w4, v_fmas(-0.75f, w2, v_scale(0.5f, w1)));
    } else if (y == NN - 2) {
        d1 = v_scale(0.5f, v_sub(w3, w1));
        d2 = v_fmas(0.25f, w0, v_fmas(-0.75f, w2, v_scale(0.5f, w3)));
    } else if (y == NN - 1) {
        d1 = v_sub(w2, w1);
        d2 = v_fmas(0.5f, w0, v_fmas(0.5f, w2, v_scale(-1.0f, w1)));
    } else {
        d1 = v_scale(0.5f, v_sub(w3, w1));
        d2 = v_scale(0.25f, v_add(v_sub(w4, v_scale(2.0f, w2)), w0));
    }
}

__device__ __forceinline__ void yder1(float4 p0, float4 p1, float4 p2, int y, float4& d1) {
    if (y == 0)           d1 = v_sub(p2, p1);
    else if (y == NN - 1) d1 = v_sub(p1, p0);
    else                  d1 = v_scale(0.5f, v_sub(p2, p0));
}

__global__ __launch_bounds__(256) void physics_residual_kernel(
    const float* __restrict__ fnow, const float* __restrict__ fnext,
    double* __restrict__ part)
{
    const int tx = threadIdx.x;            // f4 column 0..255
    const int y0 = blockIdx.x * ROWS;
    const int b  = blockIdx.y;

    const size_t cb = (size_t)b * 4 * CH + (size_t)tx * 4;
    const float* Up  = fnext + cb;
    const float* Vp  = Up + CH;
    const float* Tp  = Vp + CH;
    const float* Pp  = Tp + CH;
    const float* Unp = fnow + cb;
    const float* Vnp = Unp + CH;
    const float* Tnp = Vnp + CH;

    const int loff = (tx > 0) ? -4 : 0;            // clamped; edge values unused
    const int roff = (tx < NN / 4 - 1) ? 4 : 0;

    // ---- init rolling windows: rows y0-2 .. y0+2 (clamped) ----
    float4 U0 = ldf4(Up + (size_t)clampr(y0 - 2) * NN);
    float4 U1 = ldf4(Up + (size_t)clampr(y0 - 1) * NN);
    float4 U2 = ldf4(Up + (size_t)y0 * NN);
    float4 U3 = ldf4(Up + (size_t)clampr(y0 + 1) * NN);
    float4 U4 = ldf4(Up + (size_t)clampr(y0 + 2) * NN);
    float4 V0 = ldf4(Vp + (size_t)clampr(y0 - 2) * NN);
    float4 V1 = ldf4(Vp + (size_t)clampr(y0 - 1) * NN);
    float4 V2 = ldf4(Vp + (size_t)y0 * NN);
    float4 V3 = ldf4(Vp + (size_t)clampr(y0 + 1) * NN);
    float4 V4 = ldf4(Vp + (size_t)clampr(y0 + 2) * NN);
    float4 T0 = ldf4(Tp + (size_t)clampr(y0 - 2) * NN);
    float4 T1 = ldf4(Tp + (size_t)clampr(y0 - 1) * NN);
    float4 T2 = ldf4(Tp + (size_t)y0 * NN);
    float4 T3 = ldf4(Tp + (size_t)clampr(y0 + 1) * NN);
    float4 T4 = ldf4(Tp + (size_t)clampr(y0 + 2) * NN);
    float4 P0 = ldf4(Pp + (size_t)clampr(y0 - 1) * NN);
    float4 P1 = ldf4(Pp + (size_t)y0 * NN);
    float4 P2 = ldf4(Pp + (size_t)clampr(y0 + 1) * NN);

    float acc = 0.0f;

    #pragma unroll
    for (int k = 0; k < ROWS; ++k) {
        const int y = y0 + k;
        const size_t yrow = (size_t)y * NN;

        // ---- issue all loads for this iteration up front (independent) ----
        float4 lU = ldf4(Up + yrow + loff), rU = ldf4(Up + yrow + roff);
        float4 lV = ldf4(Vp + yrow + loff), rV = ldf4(Vp + yrow + roff);
        float4 lT = ldf4(Tp + yrow + loff), rT = ldf4(Tp + yrow + roff);
        float4 lP = ldf4(Pp + yrow + loff), rP = ldf4(Pp + yrow + roff);
        float4 cUn = ldf4(Unp + yrow);
        float4 cVn = ldf4(Vnp + yrow);
        float4 cTn = ldf4(Tnp + yrow);
        // next iteration's window rows (clamped; wasted on last iter, harmless)
        float4 nU = ldf4(Up + (size_t)clampr(y + 3) * NN);
        float4 nV = ldf4(Vp + (size_t)clampr(y + 3) * NN);
        float4 nT = ldf4(Tp + (size_t)clampr(y + 3) * NN);
        float4 nP = ldf4(Pp + (size_t)clampr(y + 2) * NN);

        // ---- derivatives ----
        float4 Udx, Udxx, Vdx, Vdxx, Tdx, Tdxx, Pdx;
        xder(lU, U2, rU, tx, Udx, Udxx);
        xder(lV, V2, rV, tx, Vdx, Vdxx);
        xder(lT, T2, rT, tx, Tdx, Tdxx);
        xder1(lP, P1, rP, tx, Pdx);

        float4 Udy, Udyy, Vdy, Vdyy, Tdy, Tdyy, Pdy;
        yder(U0, U1, U2, U3, U4, y, Udy, Udyy);
        yder(V0, V1, V2, V3, V4, y, Vdy, Vdyy);
        yder(T0, T1, T2, T3, T4, y, Tdy, Tdyy);
        yder1(P0, P1, P2, y, Pdy);

        // ---- residuals ----
        // continuity
        float4 cont = v_add(Udx, Vdy);

        // x-momentum: (u-un)*100 + u*Udx + vn*Udy + Pdx - 0.71*(Udxx+Udyy) + 7.1*u
        float4 rx = v_fmas(100.0f, v_sub(U2, cUn), Pdx);
        rx = v_fma(U2, Udx, rx);
        rx = v_fma(cVn, Udy, rx);
        rx = v_fmas(-0.71f, v_add(Udxx, Udyy), rx);
        rx = v_fmas(7.1f, U2, rx);

        // y-momentum: (v-vn)*100 + un*Vdx + v*Vdy + Pdy - 0.71*(Vdxx+Vdyy) - 710*t + 78.1*v
        float4 ry = v_fmas(100.0f, v_sub(V2, cVn), Pdy);
        ry = v_fma(cUn, Vdx, ry);
        ry = v_fma(V2, Vdy, ry);
        ry = v_fmas(-0.71f, v_add(Vdxx, Vdyy), ry);
        ry = v_fmas(-710.0f, T2, ry);
        ry = v_fmas(78.1f, V2, ry);

        // energy: (t-tn)*100 + un*Tdx + vn*Tdy - (5/3)*(Tdxx+Tdyy) - 0.1*t
        float4 rt = v_scale(100.0f, v_sub(T2, cTn));
        rt = v_fma(cUn, Tdx, rt);
        rt = v_fma(cVn, Tdy, rt);
        rt = v_fmas(-1.6666666666666667f, v_add(Tdxx, Tdyy), rt);
        rt = v_fmas(-0.1f, T2, rt);

        float4 sq = v_mul(cont, cont);
        sq = v_fma(rx, rx, sq);
        sq = v_fma(ry, ry, sq);
        sq = v_fma(rt, rt, sq);
        acc += (sq.x + sq.y) + (sq.z + sq.w);

        // ---- shift windows ----
        U0 = U1; U1 = U2; U2 = U3; U3 = U4; U4 = nU;
        V0 = V1; V1 = V2; V2 = V3; V3 = V4; V4 = nV;
        T0 = T1; T1 = T2; T2 = T3; T3 = T4; T4 = nT;
        P0 = P1; P1 = P2; P2 = nP;
    }

    // ---- block reduction: wave shuffle -> LDS -> per-block double partial ----
    double d = (double)acc;
    #pragma unroll
    for (int off = 32; off; off >>= 1) d += __shfl_down(d, off, 64);

    __shared__ double lsum[4];
    const int lane = threadIdx.x & 63;
    const int wv   = threadIdx.x >> 6;
    if (lane == 0) lsum[wv] = d;
    __syncthreads();
    if (threadIdx.x == 0) {
        part[blockIdx.y * gridDim.x + blockIdx.x] = lsum[0] + lsum[1] + lsum[2] + lsum[3];
    }
}

__global__ __launch_bounds__(1024) void final_reduce_kernel(
    const double* __restrict__ part, int n, float* __restrict__ out)
{
    double s = 0.0;
    for (int i = threadIdx.x; i < n; i += 1024) s += part[i];

    #pragma unroll
    for (int off = 32; off; off >>= 1) s += __shfl_down(s, off, 64);

    __shared__ double lsum[16];
    const int lane = threadIdx.x & 63;
    const int wv   = threadIdx.x >> 6;
    if (lane == 0) lsum[wv] = s;
    __syncthreads();
    if (threadIdx.x == 0) {
        double tot = 0.0;
        #pragma unroll
        for (int i = 0; i < 16; ++i) tot += lsum[i];
        tot *= (1e-4 / 8388608.0);   // BASE_SCALE / mean-count (same for all 4 terms)
        tot = fmin(fmax(tot, 1e-10), 1.0);
        out[0] = (float)tot;
    }
}

extern "C" void kernel_launch(void* const* d_in, const int* in_sizes, int n_in,
                              void* d_out, int out_size, void* d_ws, size_t ws_size,
                              hipStream_t stream) {
    const float* fnow  = (const float*)d_in[0];
    const float* fnext = (const float*)d_in[1];
    double* part = (double*)d_ws;          // 1024 doubles = 8 KiB scratch
    float*  out  = (float*)d_out;

    dim3 grid(NN / ROWS, 8);               // (128, 8) = 1024 blocks, 256 thr each
    physics_residual_kernel<<<grid, 256, 0, stream>>>(fnow, fnext, part);
    final_reduce_kernel<<<1, 1024, 0, stream>>>(part, grid.x * grid.y, out);
}